// Round 5
// baseline (2883.243 us; speedup 1.0000x reference)
//
#include <hip/hip_runtime.h>
#include <math.h>

#define EPSBN 1e-5f

// sums layout in d_ws (floats), replicated in NSLOT slots of stride SUMSTRIDE:
// 0: s1[16], 16: q1[16], 32: s2[16], 48: q2[16], 64: s3[12], 76: q3[12],
// 88: s4[12], 100: q4[12], 112: s5[8], 120: q5[8]   -> 128 floats per slot
constexpr int NSLOT = 8;
constexpr int SUMSTRIDE = 128;

struct P {
  const float* in;
  const float *w1,*b1,*g1,*be1;
  const float *w2,*b2,*g2,*be2;
  const float *w3,*b3,*g3,*be3;
  const float *w4,*b4,*g4,*be4;
  const float *w5,*b5,*g5,*be5;
  const float *w6,*b6;
  float* out;
  float* sums;
  int B;
};

__device__ inline float slot_sum(const float* base) {
  float s = 0.f;
  #pragma unroll
  for (int k = 0; k < NSLOT; ++k) s += base[k * SUMSTRIDE];
  return s;
}

template<int OUT, int IN>
__device__ inline void ld_raw(float* sw, float* sb, const float* __restrict__ w,
                              const float* __restrict__ b) {
  for (int t = threadIdx.x; t < OUT * IN; t += 256) sw[t] = w[t];
  if (threadIdx.x < OUT) sb[threadIdx.x] = b[threadIdx.x];
}

template<int OUT, int IN>
__device__ inline void ld_fold(float* sw, float* sb, const float* __restrict__ w,
                               const float* __restrict__ b, const float* __restrict__ g,
                               const float* __restrict__ be, const float* sum,
                               const float* sq, float invB) {
  for (int o = threadIdx.x; o < OUT; o += 256) {
    float m = slot_sum(sum + o) * invB;
    float v = slot_sum(sq + o) * invB - m * m;
    float a = g[o] * rsqrtf(v + EPSBN);
    float c = be[o] - a * m;
    sb[o] = fmaf(a, b[o], c);
  }
  for (int t = threadIdx.x; t < OUT * IN; t += 256) {
    int o = t / IN;
    float m = slot_sum(sum + o) * invB;
    float v = slot_sum(sq + o) * invB - m * m;
    float a = g[o] * rsqrtf(v + EPSBN);
    sw[t] = a * w[t];
  }
}

template<int N>
__device__ inline void accum(const float (&h)[4][N], float* accS, float* accQ) {
  #pragma unroll
  for (int o = 0; o < N; ++o) {
    #pragma unroll
    for (int r = 0; r < 4; ++r) {
      accS[o] += h[r][o];
      accQ[o] = fmaf(h[r][o], h[r][o], accQ[o]);
    }
  }
}

template<int STAGE>
__global__ __launch_bounds__(256)
void qcnn(P p) {
  __shared__ float sW1[128], sB1[16];
  __shared__ float sW2[256], sB2[16];
  __shared__ float sW3[192], sB3[12];
  __shared__ float sW4[144], sB4[12];
  __shared__ float sW5[96],  sB5[8];
  __shared__ float sW6[8],   sB6[1];
  __shared__ float red[4][32];

  const float invB = 1.0f / (float)p.B;
  if constexpr (STAGE == 1) ld_raw<16,8>(sW1, sB1, p.w1, p.b1);
  else ld_fold<16,8>(sW1, sB1, p.w1, p.b1, p.g1, p.be1, p.sums + 0, p.sums + 16, invB);
  if constexpr (STAGE >= 2) {
    if constexpr (STAGE == 2) ld_raw<16,16>(sW2, sB2, p.w2, p.b2);
    else ld_fold<16,16>(sW2, sB2, p.w2, p.b2, p.g2, p.be2, p.sums + 32, p.sums + 48, invB);
  }
  if constexpr (STAGE >= 3) {
    if constexpr (STAGE == 3) ld_raw<12,16>(sW3, sB3, p.w3, p.b3);
    else ld_fold<12,16>(sW3, sB3, p.w3, p.b3, p.g3, p.be3, p.sums + 64, p.sums + 76, invB);
  }
  if constexpr (STAGE >= 4) {
    if constexpr (STAGE == 4) ld_raw<12,12>(sW4, sB4, p.w4, p.b4);
    else ld_fold<12,12>(sW4, sB4, p.w4, p.b4, p.g4, p.be4, p.sums + 88, p.sums + 100, invB);
  }
  if constexpr (STAGE >= 5) {
    if constexpr (STAGE == 5) ld_raw<8,12>(sW5, sB5, p.w5, p.b5);
    else ld_fold<8,12>(sW5, sB5, p.w5, p.b5, p.g5, p.be5, p.sums + 112, p.sums + 120, invB);
  }
  if constexpr (STAGE == 6) ld_raw<1,8>(sW6, sB6, p.w6, p.b6);
  __syncthreads();

  constexpr int W   = (STAGE <= 2) ? 16 : (STAGE <= 4) ? 12 : 8;   // stats width
  constexpr int OFF = (STAGE == 1) ? 0 : (STAGE == 2) ? 32 : (STAGE == 3) ? 64
                    : (STAGE == 4) ? 88 : 112;

  float accS[16], accQ[16];
  if constexpr (STAGE <= 5) {
    #pragma unroll
    for (int i = 0; i < 16; ++i) { accS[i] = 0.f; accQ[i] = 0.f; }
  }

  const int tid = blockIdx.x * 256 + threadIdx.x;
  const int nthreads = gridDim.x * 256;
  const int ngroups = p.B >> 2;   // 4 rows per group

  for (int gidx = tid; gidx < ngroups; gidx += nthreads) {
    // load 4 rows of input [8 floats each], contiguous 128B per thread
    float x[4][8];
    const float4* ip = reinterpret_cast<const float4*>(p.in) + (size_t)gidx * 8;
    #pragma unroll
    for (int r = 0; r < 4; ++r) {
      float4 u0 = ip[r * 2 + 0], u1 = ip[r * 2 + 1];
      x[r][0] = u0.x; x[r][1] = u0.y; x[r][2] = u0.z; x[r][3] = u0.w;
      x[r][4] = u1.x; x[r][5] = u1.y; x[r][6] = u1.z; x[r][7] = u1.w;
    }

    float h1[4][16];
    #pragma unroll
    for (int r = 0; r < 4; ++r)
      #pragma unroll
      for (int o = 0; o < 16; ++o) {
        float s = sB1[o];
        #pragma unroll
        for (int i = 0; i < 8; ++i) s = fmaf(sW1[o * 8 + i], x[r][i], s);
        h1[r][o] = s;
      }
    if constexpr (STAGE == 1) { accum<16>(h1, accS, accQ); }
    else {
      float x1[4][16];
      #pragma unroll
      for (int r = 0; r < 4; ++r)
        #pragma unroll
        for (int o = 0; o < 16; ++o) x1[r][o] = fmaxf(h1[r][o], 0.f);

      float h2[4][16];
      #pragma unroll
      for (int r = 0; r < 4; ++r)
        #pragma unroll
        for (int o = 0; o < 16; ++o) {
          float s = sB2[o];
          #pragma unroll
          for (int i = 0; i < 16; ++i) s = fmaf(sW2[o * 16 + i], x1[r][i], s);
          h2[r][o] = s;
        }
      if constexpr (STAGE == 2) { accum<16>(h2, accS, accQ); }
      else {
        // x2 = relu(relu(h2) + x1); outer relu redundant (both terms >= 0)
        float x2[4][16];
        #pragma unroll
        for (int r = 0; r < 4; ++r)
          #pragma unroll
          for (int o = 0; o < 16; ++o) x2[r][o] = fmaxf(h2[r][o], 0.f) + x1[r][o];

        float h3[4][12];
        #pragma unroll
        for (int r = 0; r < 4; ++r)
          #pragma unroll
          for (int o = 0; o < 12; ++o) {
            float s = sB3[o];
            #pragma unroll
            for (int i = 0; i < 16; ++i) s = fmaf(sW3[o * 16 + i], x2[r][i], s);
            h3[r][o] = s;
          }
        if constexpr (STAGE == 3) { accum<12>(h3, accS, accQ); }
        else {
          float x3[4][12];
          #pragma unroll
          for (int r = 0; r < 4; ++r)
            #pragma unroll
            for (int o = 0; o < 12; ++o) x3[r][o] = fmaxf(h3[r][o], 0.f);

          float h4[4][12];
          #pragma unroll
          for (int r = 0; r < 4; ++r)
            #pragma unroll
            for (int o = 0; o < 12; ++o) {
              float s = sB4[o];
              #pragma unroll
              for (int i = 0; i < 12; ++i) s = fmaf(sW4[o * 12 + i], x3[r][i], s);
              h4[r][o] = s;
            }
          if constexpr (STAGE == 4) { accum<12>(h4, accS, accQ); }
          else {
            float x4[4][12];
            #pragma unroll
            for (int r = 0; r < 4; ++r)
              #pragma unroll
              for (int o = 0; o < 12; ++o) x4[r][o] = fmaxf(h4[r][o], 0.f) + x3[r][o];

            float h5[4][8];
            #pragma unroll
            for (int r = 0; r < 4; ++r)
              #pragma unroll
              for (int o = 0; o < 8; ++o) {
                float s = sB5[o];
                #pragma unroll
                for (int i = 0; i < 12; ++i) s = fmaf(sW5[o * 12 + i], x4[r][i], s);
                h5[r][o] = s;
              }
            if constexpr (STAGE == 5) { accum<8>(h5, accS, accQ); }
            else {
              float ov[4];
              #pragma unroll
              for (int r = 0; r < 4; ++r) {
                float z = sB6[0];
                #pragma unroll
                for (int i = 0; i < 8; ++i) z = fmaf(sW6[i], fmaxf(h5[r][i], 0.f), z);
                ov[r] = 1.0f / (1.0f + expf(-z));
              }
              reinterpret_cast<float4*>(p.out)[gidx] =
                  make_float4(ov[0], ov[1], ov[2], ov[3]);
            }
          }
        }
      }
    }
  }

  if constexpr (STAGE <= 5) {
    const int lane = threadIdx.x & 63;
    const int wv = threadIdx.x >> 6;
    #pragma unroll
    for (int v = 0; v < 2 * W; ++v) {
      float val = (v < W) ? accS[v] : accQ[v - W];
      #pragma unroll
      for (int d = 1; d < 64; d <<= 1) val += __shfl_xor(val, d, 64);
      if (lane == 0) red[wv][v] = val;
    }
    __syncthreads();
    if (threadIdx.x < 2 * W) {
      float f = red[0][threadIdx.x] + red[1][threadIdx.x] +
                red[2][threadIdx.x] + red[3][threadIdx.x];
      const int slot = blockIdx.x & (NSLOT - 1);
      atomicAdd(p.sums + slot * SUMSTRIDE + OFF + threadIdx.x, f);
    }
  }
}

extern "C" void kernel_launch(void* const* d_in, const int* in_sizes, int n_in,
                              void* d_out, int out_size, void* d_ws, size_t ws_size,
                              hipStream_t stream) {
  P p;
  p.in  = (const float*)d_in[0];
  p.w1 = (const float*)d_in[1];  p.b1 = (const float*)d_in[2];
  p.g1 = (const float*)d_in[3];  p.be1 = (const float*)d_in[4];
  p.w2 = (const float*)d_in[5];  p.b2 = (const float*)d_in[6];
  p.g2 = (const float*)d_in[7];  p.be2 = (const float*)d_in[8];
  p.w3 = (const float*)d_in[9];  p.b3 = (const float*)d_in[10];
  p.g3 = (const float*)d_in[11]; p.be3 = (const float*)d_in[12];
  p.w4 = (const float*)d_in[13]; p.b4 = (const float*)d_in[14];
  p.g4 = (const float*)d_in[15]; p.be4 = (const float*)d_in[16];
  p.w5 = (const float*)d_in[17]; p.b5 = (const float*)d_in[18];
  p.g5 = (const float*)d_in[19]; p.be5 = (const float*)d_in[20];
  p.w6 = (const float*)d_in[21]; p.b6 = (const float*)d_in[22];
  p.out = (float*)d_out;
  p.sums = (float*)d_ws;
  p.B = in_sizes[0] / 8;

  hipMemsetAsync(d_ws, 0, NSLOT * SUMSTRIDE * sizeof(float), stream);

  const dim3 grid(1024), block(256);
  qcnn<1><<<grid, block, 0, stream>>>(p);
  qcnn<2><<<grid, block, 0, stream>>>(p);
  qcnn<3><<<grid, block, 0, stream>>>(p);
  qcnn<4><<<grid, block, 0, stream>>>(p);
  qcnn<5><<<grid, block, 0, stream>>>(p);
  qcnn<6><<<grid, block, 0, stream>>>(p);
}